// Round 1
// baseline (533.094 us; speedup 1.0000x reference)
//
#include <hip/hip_runtime.h>

// Problem constants (B=8, T=4096, D=64, M=1024, N=32768)
#define T_DIM 4096
#define D_DIM 64
#define M_DIM 1024
#define N_ROWS 32768
#define TR 16  // rows (tokens) per workgroup

// ws layout (floats): [0,1024) = ||e_m||^2 ; [1024,2048) = hard-assign counts ; [2048] = loss accum

__global__ void vq_prep(const float* __restrict__ emb, float* __restrict__ ws) {
  int m = blockIdx.x * 256 + threadIdx.x;  // 4 blocks * 256 = 1024
  const float* e = emb + (size_t)m * D_DIM;
  float s = 0.f;
#pragma unroll
  for (int d = 0; d < D_DIM; d += 4) {
    float4 v = *(const float4*)(e + d);
    s += v.x * v.x + v.y * v.y + v.z * v.z + v.w * v.w;
  }
  ws[m] = s;
  ws[M_DIM + m] = 0.f;
  if (m == 0) ws[2 * M_DIM] = 0.f;
}

__global__ __launch_bounds__(256, 2) void vq_main(
    const float* __restrict__ x, const float* __restrict__ emb,
    const float* __restrict__ lvq, const float* __restrict__ gum,
    const float* __restrict__ temp, float* __restrict__ outq,
    float* __restrict__ ws) {
  __shared__ float s_sc[TR][M_DIM + 4];  // logits, then overwritten with encodings
  __shared__ float s_x[TR][68];          // x tile (padded)
  __shared__ float s_xx[TR];
  __shared__ float s_red[4];

  const int tid = threadIdx.x;
  const int n0 = blockIdx.x * TR;     // tile always within one batch (T%TR==0)
  const int b = n0 >> 12;             // n / 4096
  const int t0 = n0 & (T_DIM - 1);
  const float precision = __expf(-lvq[0]);
  const float inv_temp = 1.0f / temp[0];
  const float* eew = ws;
  float* counts = ws + M_DIM;
  float* accum = ws + 2 * M_DIM;

  // ---- stage x tile: x[b][d][t0+tt] ----
  {
    int tt = tid & 15, d0 = tid >> 4;
    const float* xb = x + ((size_t)b << 18) + (size_t)(t0 + tt);
#pragma unroll
    for (int k = 0; k < 4; ++k) {
      int d = d0 + 16 * k;
      s_x[tt][d] = xb[(size_t)d << 12];
    }
  }
  __syncthreads();
  if (tid < TR) {
    float s = 0.f;
#pragma unroll
    for (int d = 0; d < D_DIM; ++d) { float v = s_x[tid][d]; s += v * v; }
    s_xx[tid] = s;
  }
  __syncthreads();

  // ---- phase 1: logits[r][m] = precision*(x.e - 0.5||x||^2 - 0.5||e||^2) ----
  // thread tid owns m = 4*tid .. 4*tid+3 for all 16 rows
  {
    float4 ee4 = *(const float4*)(eew + 4 * tid);
    float acc[TR][4];
#pragma unroll
    for (int r = 0; r < TR; ++r) {
      acc[r][0] = -0.5f * (s_xx[r] + ee4.x);
      acc[r][1] = -0.5f * (s_xx[r] + ee4.y);
      acc[r][2] = -0.5f * (s_xx[r] + ee4.z);
      acc[r][3] = -0.5f * (s_xx[r] + ee4.w);
    }
    const float* e0 = emb + (size_t)tid * 256;  // 4 embedding rows per thread
    for (int d4 = 0; d4 < D_DIM; d4 += 4) {
      float4 ea = *(const float4*)(e0 + d4);
      float4 eb = *(const float4*)(e0 + 64 + d4);
      float4 ec = *(const float4*)(e0 + 128 + d4);
      float4 ed = *(const float4*)(e0 + 192 + d4);
#pragma unroll
      for (int r = 0; r < TR; ++r) {
        float4 xv = *(const float4*)&s_x[r][d4];
        acc[r][0] += xv.x * ea.x + xv.y * ea.y + xv.z * ea.z + xv.w * ea.w;
        acc[r][1] += xv.x * eb.x + xv.y * eb.y + xv.z * eb.z + xv.w * eb.w;
        acc[r][2] += xv.x * ec.x + xv.y * ec.y + xv.z * ec.z + xv.w * ec.w;
        acc[r][3] += xv.x * ed.x + xv.y * ed.y + xv.z * ed.z + xv.w * ed.w;
      }
    }
#pragma unroll
    for (int r = 0; r < TR; ++r) {
      float4 v;
      v.x = precision * acc[r][0];
      v.y = precision * acc[r][1];
      v.z = precision * acc[r][2];
      v.w = precision * acc[r][3];
      *(float4*)&s_sc[r][4 * tid] = v;
    }
  }
  __syncthreads();

  const int lane = tid & 63;
  const int wave = tid >> 6;
  float partial = 0.f;

  // ---- phase 2: per-row softmaxes (wave w handles rows 4w..4w+3) ----
  for (int rr = 0; rr < 4; ++rr) {
    int r = wave * 4 + rr;
    int n = n0 + r;
    float s[16], g[16];
    // lane l owns m = 4l + 256k + j (ascending within lane)
#pragma unroll
    for (int k = 0; k < 4; ++k) {
      float4 v = *(const float4*)&s_sc[r][4 * lane + 256 * k];
      s[4 * k + 0] = v.x; s[4 * k + 1] = v.y; s[4 * k + 2] = v.z; s[4 * k + 3] = v.w;
    }
    // argmax of logits == argmin of distances (first index on ties)
    float mx = -1e30f; int mi = 0;
#pragma unroll
    for (int i = 0; i < 16; ++i) {
      int m = 4 * lane + 256 * (i >> 2) + (i & 3);
      if (s[i] > mx) { mx = s[i]; mi = m; }
    }
#pragma unroll
    for (int off = 32; off; off >>= 1) {
      float omx = __shfl_xor(mx, off);
      int omi = __shfl_xor(mi, off);
      if (omx > mx || (omx == mx && omi < mi)) { mx = omx; mi = omi; }
    }
    const float* gn = gum + ((size_t)n << 10);
#pragma unroll
    for (int k = 0; k < 4; ++k) {
      float4 v = *(const float4*)(gn + 4 * lane + 256 * k);
      g[4 * k + 0] = v.x; g[4 * k + 1] = v.y; g[4 * k + 2] = v.z; g[4 * k + 3] = v.w;
    }
    float gmx = -1e30f;
#pragma unroll
    for (int i = 0; i < 16; ++i) {
      float gv = (s[i] + g[i]) * inv_temp;
      g[i] = gv;
      gmx = fmaxf(gmx, gv);
    }
#pragma unroll
    for (int off = 32; off; off >>= 1) gmx = fmaxf(gmx, __shfl_xor(gmx, off));
    float Zs = 0.f, As = 0.f, Zg = 0.f;
#pragma unroll
    for (int i = 0; i < 16; ++i) {
      float a = s[i] - mx;
      float e = __expf(a);
      Zs += e; As += a * e;
      float eg = __expf(g[i] - gmx);
      g[i] = eg;
      Zg += eg;
    }
#pragma unroll
    for (int off = 32; off; off >>= 1) {
      Zs += __shfl_xor(Zs, off);
      As += __shfl_xor(As, off);
      Zg += __shfl_xor(Zg, off);
    }
    float invZg = 1.0f / Zg;
#pragma unroll
    for (int k = 0; k < 4; ++k) {
      float4 w;
      w.x = g[4 * k + 0] * invZg; w.y = g[4 * k + 1] * invZg;
      w.z = g[4 * k + 2] * invZg; w.w = g[4 * k + 3] * invZg;
      *(float4*)&s_sc[r][4 * lane + 256 * k] = w;  // encodings overwrite logits
    }
    if (lane == 0) {
      partial += As / Zs - __logf(Zs);  // sum p*log p for this row
      atomicAdd(counts + mi, 1.0f);
    }
  }
  __syncthreads();

  // ---- phase 3: quantized[r][d] = sum_m w[r][m] * e[m][d]; write transposed; recon ----
  {
    int r = tid >> 4, dq = tid & 15;
    float qx = 0.f, qy = 0.f, qz = 0.f, qw = 0.f;
    const float* ecol = emb + 4 * dq;
    for (int m4 = 0; m4 < M_DIM; m4 += 4) {
      float4 w4 = *(const float4*)&s_sc[r][m4];
      float4 e0 = *(const float4*)(ecol + (size_t)(m4 + 0) * 64);
      float4 e1 = *(const float4*)(ecol + (size_t)(m4 + 1) * 64);
      float4 e2 = *(const float4*)(ecol + (size_t)(m4 + 2) * 64);
      float4 e3 = *(const float4*)(ecol + (size_t)(m4 + 3) * 64);
      qx += w4.x * e0.x + w4.y * e1.x + w4.z * e2.x + w4.w * e3.x;
      qy += w4.x * e0.y + w4.y * e1.y + w4.z * e2.y + w4.w * e3.y;
      qz += w4.x * e0.z + w4.y * e1.z + w4.z * e2.z + w4.w * e3.z;
      qw += w4.x * e0.w + w4.y * e1.w + w4.z * e2.w + w4.w * e3.w;
    }
    int t = t0 + r;
    float* ob = outq + ((size_t)b << 18) + (size_t)t;
    int d = 4 * dq;
    ob[(size_t)(d + 0) << 12] = qx;
    ob[(size_t)(d + 1) << 12] = qy;
    ob[(size_t)(d + 2) << 12] = qz;
    ob[(size_t)(d + 3) << 12] = qw;
    float4 xv = *(const float4*)&s_x[r][d];
    float dx0 = xv.x - qx, dx1 = xv.y - qy, dx2 = xv.z - qz, dx3 = xv.w - qw;
    partial += 0.5f * precision * (dx0 * dx0 + dx1 * dx1 + dx2 * dx2 + dx3 * dx3);
  }
#pragma unroll
  for (int off = 32; off; off >>= 1) partial += __shfl_xor(partial, off);
  if (lane == 0) s_red[wave] = partial;
  __syncthreads();
  if (tid == 0) atomicAdd(accum, s_red[0] + s_red[1] + s_red[2] + s_red[3]);
}

__global__ void vq_finalize(const float* __restrict__ ws, float* __restrict__ out) {
  __shared__ float red[4];
  int tid = threadIdx.x;
  float h = 0.f;
  for (int m = tid; m < M_DIM; m += 256) {
    float avg = ws[M_DIM + m] * (1.0f / 32768.0f);
    h += avg * __logf(avg + 1e-10f);
  }
#pragma unroll
  for (int off = 32; off; off >>= 1) h += __shfl_xor(h, off);
  int lane = tid & 63, wave = tid >> 6;
  if (lane == 0) red[wave] = h;
  __syncthreads();
  if (tid == 0) {
    out[0] = ws[2 * M_DIM] * 0.125f;                   // loss = total / B
    out[1] = __expf(-(red[0] + red[1] + red[2] + red[3]));  // perplexity
  }
}

extern "C" void kernel_launch(void* const* d_in, const int* in_sizes, int n_in,
                              void* d_out, int out_size, void* d_ws, size_t ws_size,
                              hipStream_t stream) {
  const float* x = (const float*)d_in[0];
  const float* emb = (const float*)d_in[1];
  const float* lvq = (const float*)d_in[2];
  const float* gum = (const float*)d_in[3];
  const float* temp = (const float*)d_in[4];
  float* out = (float*)d_out;
  float* ws = (float*)d_ws;

  hipLaunchKernelGGL(vq_prep, dim3(4), dim3(256), 0, stream, emb, ws);
  hipLaunchKernelGGL(vq_main, dim3(N_ROWS / TR), dim3(256), 0, stream,
                     x, emb, lvq, gum, temp, out, ws);
  hipLaunchKernelGGL(vq_finalize, dim3(1), dim3(256), 0, stream, ws,
                     out + (size_t)2097152);
}

// Round 2
// 500.219 us; speedup vs baseline: 1.0657x; 1.0657x over previous
//
#include <hip/hip_runtime.h>

// Problem constants (B=8, T=4096, D=64, M=1024, N=32768)
#define T_DIM 4096
#define D_DIM 64
#define M_DIM 1024
#define N_ROWS 32768
#define TR 16   // rows (tokens) per workgroup
#define NT 512  // threads per block

// ws layout (floats): [0,1024) = ||e_m||^2 ; [1024,2048) = hard-assign counts ; [2048] = loss accum

__global__ void vq_prep(const float* __restrict__ emb, float* __restrict__ ws) {
  int m = blockIdx.x * 256 + threadIdx.x;  // 4 blocks * 256 = 1024
  const float* e = emb + (size_t)m * D_DIM;
  float s = 0.f;
#pragma unroll
  for (int d = 0; d < D_DIM; d += 4) {
    float4 v = *(const float4*)(e + d);
    s += v.x * v.x + v.y * v.y + v.z * v.z + v.w * v.w;
  }
  ws[m] = s;
  ws[M_DIM + m] = 0.f;
  if (m == 0) ws[2 * M_DIM] = 0.f;
}

__global__ __launch_bounds__(NT, 4) void vq_main(
    const float* __restrict__ x, const float* __restrict__ emb,
    const float* __restrict__ lvq, const float* __restrict__ gum,
    const float* __restrict__ temp, float* __restrict__ outq,
    float* __restrict__ ws) {
  __shared__ float s_sc[TR][M_DIM + 4];   // logits, then encodings
  __shared__ float s_x[TR][68];           // x tile (padded)
  __shared__ float s_xx[TR];
  __shared__ float s_red[8];
  __shared__ float s_part[4][TR][17];     // phase-3 half-0 partials (padded)

  const int tid = threadIdx.x;
  const int n0 = blockIdx.x * TR;     // tile always within one batch (T%TR==0)
  const int b = n0 >> 12;             // n / 4096
  const int t0 = n0 & (T_DIM - 1);
  const float precision = __expf(-lvq[0]);
  const float inv_temp = 1.0f / temp[0];
  const float* eew = ws;
  float* counts = ws + M_DIM;
  float* accum = ws + 2 * M_DIM;

  // ---- stage x tile: x[b][d][t0+tt] ----
  {
    int tt = tid & 15, d0 = tid >> 4;   // d0 in [0,32)
    const float* xb = x + ((size_t)b << 18) + (size_t)(t0 + tt);
    s_x[tt][d0] = xb[(size_t)d0 << 12];
    s_x[tt][d0 + 32] = xb[(size_t)(d0 + 32) << 12];
  }
  __syncthreads();
  if (tid < TR) {
    float s = 0.f;
#pragma unroll
    for (int d = 0; d < D_DIM; ++d) { float v = s_x[tid][d]; s += v * v; }
    s_xx[tid] = s;
  }
  __syncthreads();

  // ---- phase 1: logits[r][m] = precision*(x.e - 0.5||x||^2 - 0.5||e||^2) ----
  // thread tid owns m = 2*tid, 2*tid+1 for all 16 rows
  {
    float2 ee2 = *(const float2*)(eew + 2 * tid);
    float acc[TR][2];
#pragma unroll
    for (int r = 0; r < TR; ++r) {
      acc[r][0] = -0.5f * (s_xx[r] + ee2.x);
      acc[r][1] = -0.5f * (s_xx[r] + ee2.y);
    }
    const float* e0 = emb + (size_t)tid * 128;  // 2 embedding rows per thread
#pragma unroll 4
    for (int d4 = 0; d4 < D_DIM; d4 += 4) {
      float4 ea = *(const float4*)(e0 + d4);
      float4 eb = *(const float4*)(e0 + 64 + d4);
#pragma unroll
      for (int r = 0; r < TR; ++r) {
        float4 xv = *(const float4*)&s_x[r][d4];
        acc[r][0] += xv.x * ea.x + xv.y * ea.y + xv.z * ea.z + xv.w * ea.w;
        acc[r][1] += xv.x * eb.x + xv.y * eb.y + xv.z * eb.z + xv.w * eb.w;
      }
    }
#pragma unroll
    for (int r = 0; r < TR; ++r) {
      float2 v;
      v.x = precision * acc[r][0];
      v.y = precision * acc[r][1];
      *(float2*)&s_sc[r][2 * tid] = v;
    }
  }
  __syncthreads();

  const int lane = tid & 63;
  const int wave = tid >> 6;   // 8 waves
  float partial = 0.f;

  // ---- phase 2: per-row softmaxes (wave w handles rows 2w, 2w+1) ----
  for (int rr = 0; rr < 2; ++rr) {
    int r = wave * 2 + rr;
    int n = n0 + r;
    float s[16], g[16];
    // lane l owns m = 4l + 256k + j (ascending within lane)
#pragma unroll
    for (int k = 0; k < 4; ++k) {
      float4 v = *(const float4*)&s_sc[r][4 * lane + 256 * k];
      s[4 * k + 0] = v.x; s[4 * k + 1] = v.y; s[4 * k + 2] = v.z; s[4 * k + 3] = v.w;
    }
    // argmax of logits == argmin of distances (first index on ties)
    float mx = -1e30f; int mi = 0;
#pragma unroll
    for (int i = 0; i < 16; ++i) {
      int m = 4 * lane + 256 * (i >> 2) + (i & 3);
      if (s[i] > mx) { mx = s[i]; mi = m; }
    }
#pragma unroll
    for (int off = 32; off; off >>= 1) {
      float omx = __shfl_xor(mx, off);
      int omi = __shfl_xor(mi, off);
      if (omx > mx || (omx == mx && omi < mi)) { mx = omx; mi = omi; }
    }
    const float* gn = gum + ((size_t)n << 10);
#pragma unroll
    for (int k = 0; k < 4; ++k) {
      float4 v = *(const float4*)(gn + 4 * lane + 256 * k);
      g[4 * k + 0] = v.x; g[4 * k + 1] = v.y; g[4 * k + 2] = v.z; g[4 * k + 3] = v.w;
    }
    float gmx = -1e30f;
#pragma unroll
    for (int i = 0; i < 16; ++i) {
      float gv = (s[i] + g[i]) * inv_temp;
      g[i] = gv;
      gmx = fmaxf(gmx, gv);
    }
#pragma unroll
    for (int off = 32; off; off >>= 1) gmx = fmaxf(gmx, __shfl_xor(gmx, off));
    float Zs = 0.f, As = 0.f, Zg = 0.f;
#pragma unroll
    for (int i = 0; i < 16; ++i) {
      float a = s[i] - mx;
      float e = __expf(a);
      Zs += e; As += a * e;
      float eg = __expf(g[i] - gmx);
      g[i] = eg;
      Zg += eg;
    }
#pragma unroll
    for (int off = 32; off; off >>= 1) {
      Zs += __shfl_xor(Zs, off);
      As += __shfl_xor(As, off);
      Zg += __shfl_xor(Zg, off);
    }
    float invZg = 1.0f / Zg;
#pragma unroll
    for (int k = 0; k < 4; ++k) {
      float4 w;
      w.x = g[4 * k + 0] * invZg; w.y = g[4 * k + 1] * invZg;
      w.z = g[4 * k + 2] * invZg; w.w = g[4 * k + 3] * invZg;
      *(float4*)&s_sc[r][4 * lane + 256 * k] = w;  // encodings overwrite logits
    }
    if (lane == 0) {
      partial += As / Zs - __logf(Zs);  // sum p*log p for this row
      atomicAdd(counts + mi, 1.0f);
    }
  }
  __syncthreads();

  // ---- phase 3: quantized[r][d] = sum_m w[r][m]*e[m][d]; write transposed; recon ----
  {
    int half = tid >> 8;           // 0/1: splits the m-range
    int rem = tid & 255;
    int r = rem >> 4, dq = rem & 15;
    float qx = 0.f, qy = 0.f, qz = 0.f, qw = 0.f;
    const float* ecol = emb + 4 * dq;
    int m0 = half * 512;
#pragma unroll 4
    for (int m4 = m0; m4 < m0 + 512; m4 += 4) {
      float4 w4 = *(const float4*)&s_sc[r][m4];
      float4 e0 = *(const float4*)(ecol + (size_t)(m4 + 0) * 64);
      float4 e1 = *(const float4*)(ecol + (size_t)(m4 + 1) * 64);
      float4 e2 = *(const float4*)(ecol + (size_t)(m4 + 2) * 64);
      float4 e3 = *(const float4*)(ecol + (size_t)(m4 + 3) * 64);
      qx += w4.x * e0.x + w4.y * e1.x + w4.z * e2.x + w4.w * e3.x;
      qy += w4.x * e0.y + w4.y * e1.y + w4.z * e2.y + w4.w * e3.y;
      qz += w4.x * e0.z + w4.y * e1.z + w4.z * e2.z + w4.w * e3.z;
      qw += w4.x * e0.w + w4.y * e1.w + w4.z * e2.w + w4.w * e3.w;
    }
    if (half == 0) {
      s_part[0][r][dq] = qx;
      s_part[1][r][dq] = qy;
      s_part[2][r][dq] = qz;
      s_part[3][r][dq] = qw;
    }
    __syncthreads();
    if (half == 1) {
      qx += s_part[0][r][dq];
      qy += s_part[1][r][dq];
      qz += s_part[2][r][dq];
      qw += s_part[3][r][dq];
      int t = t0 + r;
      float* ob = outq + ((size_t)b << 18) + (size_t)t;
      int d = 4 * dq;
      ob[(size_t)(d + 0) << 12] = qx;
      ob[(size_t)(d + 1) << 12] = qy;
      ob[(size_t)(d + 2) << 12] = qz;
      ob[(size_t)(d + 3) << 12] = qw;
      float4 xv = *(const float4*)&s_x[r][d];
      float dx0 = xv.x - qx, dx1 = xv.y - qy, dx2 = xv.z - qz, dx3 = xv.w - qw;
      partial += 0.5f * precision * (dx0 * dx0 + dx1 * dx1 + dx2 * dx2 + dx3 * dx3);
    }
  }
#pragma unroll
  for (int off = 32; off; off >>= 1) partial += __shfl_xor(partial, off);
  if (lane == 0) s_red[wave] = partial;
  __syncthreads();
  if (tid == 0) {
    float s = 0.f;
#pragma unroll
    for (int w = 0; w < 8; ++w) s += s_red[w];
    atomicAdd(accum, s);
  }
}

__global__ void vq_finalize(const float* __restrict__ ws, float* __restrict__ out) {
  __shared__ float red[4];
  int tid = threadIdx.x;
  float h = 0.f;
  for (int m = tid; m < M_DIM; m += 256) {
    float avg = ws[M_DIM + m] * (1.0f / 32768.0f);
    h += avg * __logf(avg + 1e-10f);
  }
#pragma unroll
  for (int off = 32; off; off >>= 1) h += __shfl_xor(h, off);
  int lane = tid & 63, wave = tid >> 6;
  if (lane == 0) red[wave] = h;
  __syncthreads();
  if (tid == 0) {
    out[0] = ws[2 * M_DIM] * 0.125f;                        // loss = total / B
    out[1] = __expf(-(red[0] + red[1] + red[2] + red[3]));  // perplexity
  }
}

extern "C" void kernel_launch(void* const* d_in, const int* in_sizes, int n_in,
                              void* d_out, int out_size, void* d_ws, size_t ws_size,
                              hipStream_t stream) {
  const float* x = (const float*)d_in[0];
  const float* emb = (const float*)d_in[1];
  const float* lvq = (const float*)d_in[2];
  const float* gum = (const float*)d_in[3];
  const float* temp = (const float*)d_in[4];
  float* out = (float*)d_out;
  float* ws = (float*)d_ws;

  hipLaunchKernelGGL(vq_prep, dim3(4), dim3(256), 0, stream, emb, ws);
  hipLaunchKernelGGL(vq_main, dim3(N_ROWS / TR), dim3(NT), 0, stream,
                     x, emb, lvq, gum, temp, out, ws);
  hipLaunchKernelGGL(vq_finalize, dim3(1), dim3(256), 0, stream, ws,
                     out + (size_t)2097152);
}

// Round 3
// 367.755 us; speedup vs baseline: 1.4496x; 1.3602x over previous
//
#include <hip/hip_runtime.h>

// Problem constants (B=8, T=4096, D=64, M=1024, N=32768)
#define T_DIM 4096
#define D_DIM 64
#define M_DIM 1024
#define N_ROWS 32768
#define TR 16   // rows (tokens) per workgroup
#define SC_STRIDE (M_DIM + 4)

typedef __attribute__((ext_vector_type(8))) short bf16x8;
typedef __attribute__((ext_vector_type(4))) float f32x4;

// ws layout: floats [0,1024)=||e||^2, [1024,2048)=counts, [2048]=loss accum.
// shorts from float index 4096 (byte 16384): EH[65536], EL[65536], ETH[65536], ETL[65536]
#define WS_BF16_OFF 4096

__device__ __forceinline__ short f2bfs(float f) {
  union { float f; unsigned u; } v; v.f = f;
  unsigned r = v.u + 0x7fffu + ((v.u >> 16) & 1u);  // RNE
  return (short)(r >> 16);
}
__device__ __forceinline__ float bf2f(short h) {
  union { unsigned u; float f; } v; v.u = ((unsigned)(unsigned short)h) << 16;
  return v.f;
}
// 8 consecutive fp32 -> hi/lo bf16x8
__device__ __forceinline__ void cvt8(const float* p, bf16x8& h8, bf16x8& l8) {
  float4 a = *(const float4*)p, b = *(const float4*)(p + 4);
  float v[8] = {a.x, a.y, a.z, a.w, b.x, b.y, b.z, b.w};
#pragma unroll
  for (int i = 0; i < 8; ++i) {
    short h = f2bfs(v[i]);
    h8[i] = h;
    l8[i] = f2bfs(v[i] - bf2f(h));
  }
}

__global__ void vq_prep(const float* __restrict__ emb, float* __restrict__ ws) {
  int m = blockIdx.x * 256 + threadIdx.x;  // 4 blocks * 256 = 1024
  const float* e = emb + (size_t)m * D_DIM;
  float s = 0.f;
#pragma unroll
  for (int d = 0; d < D_DIM; d += 4) {
    float4 v = *(const float4*)(e + d);
    s += v.x * v.x + v.y * v.y + v.z * v.z + v.w * v.w;
  }
  ws[m] = s;
  ws[M_DIM + m] = 0.f;
  if (m == 0) ws[2 * M_DIM] = 0.f;
}

// split embedding into hi/lo bf16, row-major and transposed
__global__ void vq_conv(const float* __restrict__ emb, float* __restrict__ ws) {
  int g = blockIdx.x * 256 + threadIdx.x;  // 256 blocks -> 65536
  int m = g >> 6, d = g & 63;
  short* EH = (short*)(ws + WS_BF16_OFF);
  short* EL = EH + 65536;
  short* ETH = EL + 65536;
  short* ETL = ETH + 65536;
  float v = emb[g];
  short h = f2bfs(v);
  short l = f2bfs(v - bf2f(h));
  EH[g] = h; EL[g] = l;
  ETH[d * 1024 + m] = h; ETL[d * 1024 + m] = l;
}

__global__ __launch_bounds__(256, 2) void vq_main(
    const float* __restrict__ x, const float* __restrict__ emb,
    const float* __restrict__ lvq, const float* __restrict__ gum,
    const float* __restrict__ temp, float* __restrict__ outq,
    float* __restrict__ ws) {
  __shared__ float s_sc[TR][SC_STRIDE];  // logits -> encodings -> q-partials
  __shared__ float s_x[TR][68];          // x tile (padded)
  __shared__ float s_xx[TR];
  __shared__ float s_red[4];

  const int tid = threadIdx.x;
  const int lane = tid & 63;
  const int wave = tid >> 6;   // 4 waves
  const int mq = lane >> 4;    // quad 0..3
  const int mn = lane & 15;
  const int n0 = blockIdx.x * TR;
  const int b = n0 >> 12;
  const int t0 = n0 & (T_DIM - 1);
  const float precision = __expf(-lvq[0]);
  const float inv_temp = 1.0f / temp[0];
  const float* eew = ws;
  float* counts = ws + M_DIM;
  float* accum = ws + 2 * M_DIM;
  const short* EH = (const short*)(ws + WS_BF16_OFF);
  const short* EL = EH + 65536;
  const short* ETH = EL + 65536;
  const short* ETL = ETH + 65536;

  // ---- stage x tile: x[b][d][t0+tt] ----
  {
    int tt = tid & 15, d0 = tid >> 4;
    const float* xb = x + ((size_t)b << 18) + (size_t)(t0 + tt);
#pragma unroll
    for (int k = 0; k < 4; ++k) {
      int d = d0 + 16 * k;
      s_x[tt][d] = xb[(size_t)d << 12];
    }
  }
  __syncthreads();
  if (tid < TR) {
    float s = 0.f;
#pragma unroll
    for (int d = 0; d < D_DIM; ++d) { float v = s_x[tid][d]; s += v * v; }
    s_xx[tid] = s;
  }
  __syncthreads();

  // ---- GEMM1 (MFMA): logits[r][m] = precision*(x.e - 0.5||x||^2 - 0.5||e||^2)
  // wave w owns m in [256w, 256w+256) = 16 tiles of 16x16; K=64 = 2 k-steps
  {
    bf16x8 ah0, al0, ah1, al1;
    cvt8(&s_x[mn][mq * 8], ah0, al0);        // k-step 0 (k = mq*8..+8)
    cvt8(&s_x[mn][32 + mq * 8], ah1, al1);   // k-step 1
    f32x4 acc[16];
#pragma unroll
    for (int tt = 0; tt < 16; ++tt) acc[tt] = (f32x4){0.f, 0.f, 0.f, 0.f};
#pragma unroll 4
    for (int tt = 0; tt < 16; ++tt) {
      int m0 = wave * 256 + tt * 16;
      const short* bp = EH + (m0 + mn) * 64 + mq * 8;
      const short* lp = EL + (m0 + mn) * 64 + mq * 8;
      bf16x8 bh0 = *(const bf16x8*)bp;
      bf16x8 bh1 = *(const bf16x8*)(bp + 32);
      bf16x8 bl0 = *(const bf16x8*)lp;
      bf16x8 bl1 = *(const bf16x8*)(lp + 32);
      acc[tt] = __builtin_amdgcn_mfma_f32_16x16x32_bf16(ah0, bh0, acc[tt], 0, 0, 0);
      acc[tt] = __builtin_amdgcn_mfma_f32_16x16x32_bf16(ah1, bh1, acc[tt], 0, 0, 0);
      acc[tt] = __builtin_amdgcn_mfma_f32_16x16x32_bf16(al0, bh0, acc[tt], 0, 0, 0);
      acc[tt] = __builtin_amdgcn_mfma_f32_16x16x32_bf16(al1, bh1, acc[tt], 0, 0, 0);
      acc[tt] = __builtin_amdgcn_mfma_f32_16x16x32_bf16(ah0, bl0, acc[tt], 0, 0, 0);
      acc[tt] = __builtin_amdgcn_mfma_f32_16x16x32_bf16(ah1, bl1, acc[tt], 0, 0, 0);
    }
    // epilogue: C layout col=lane&15, row=(lane>>4)*4+reg
#pragma unroll 4
    for (int tt = 0; tt < 16; ++tt) {
      int m0 = wave * 256 + tt * 16;
      float eev = eew[m0 + mn];
#pragma unroll
      for (int reg = 0; reg < 4; ++reg) {
        int r = mq * 4 + reg;
        s_sc[r][m0 + mn] = precision * (acc[tt][reg] - 0.5f * (s_xx[r] + eev));
      }
    }
  }
  __syncthreads();

  float partial = 0.f;

  // ---- phase 2: per-row softmaxes (wave w handles rows 4w..4w+3) ----
  for (int rr = 0; rr < 4; ++rr) {
    int r = wave * 4 + rr;
    int n = n0 + r;
    float s[16], g[16];
#pragma unroll
    for (int k = 0; k < 4; ++k) {
      float4 v = *(const float4*)&s_sc[r][4 * lane + 256 * k];
      s[4 * k + 0] = v.x; s[4 * k + 1] = v.y; s[4 * k + 2] = v.z; s[4 * k + 3] = v.w;
    }
    float mx = -1e30f; int mi = 0;
#pragma unroll
    for (int i = 0; i < 16; ++i) {
      int m = 4 * lane + 256 * (i >> 2) + (i & 3);
      if (s[i] > mx) { mx = s[i]; mi = m; }
    }
#pragma unroll
    for (int off = 32; off; off >>= 1) {
      float omx = __shfl_xor(mx, off);
      int omi = __shfl_xor(mi, off);
      if (omx > mx || (omx == mx && omi < mi)) { mx = omx; mi = omi; }
    }
    const float* gn = gum + ((size_t)n << 10);
#pragma unroll
    for (int k = 0; k < 4; ++k) {
      float4 v = *(const float4*)(gn + 4 * lane + 256 * k);
      g[4 * k + 0] = v.x; g[4 * k + 1] = v.y; g[4 * k + 2] = v.z; g[4 * k + 3] = v.w;
    }
    float gmx = -1e30f;
#pragma unroll
    for (int i = 0; i < 16; ++i) {
      float gv = (s[i] + g[i]) * inv_temp;
      g[i] = gv;
      gmx = fmaxf(gmx, gv);
    }
#pragma unroll
    for (int off = 32; off; off >>= 1) gmx = fmaxf(gmx, __shfl_xor(gmx, off));
    float Zs = 0.f, As = 0.f, Zg = 0.f;
#pragma unroll
    for (int i = 0; i < 16; ++i) {
      float a = s[i] - mx;
      float e = __expf(a);
      Zs += e; As += a * e;
      float eg = __expf(g[i] - gmx);
      g[i] = eg;
      Zg += eg;
    }
#pragma unroll
    for (int off = 32; off; off >>= 1) {
      Zs += __shfl_xor(Zs, off);
      As += __shfl_xor(As, off);
      Zg += __shfl_xor(Zg, off);
    }
    float invZg = 1.0f / Zg;
#pragma unroll
    for (int k = 0; k < 4; ++k) {
      float4 w;
      w.x = g[4 * k + 0] * invZg; w.y = g[4 * k + 1] * invZg;
      w.z = g[4 * k + 2] * invZg; w.w = g[4 * k + 3] * invZg;
      *(float4*)&s_sc[r][4 * lane + 256 * k] = w;  // encodings overwrite logits
    }
    if (lane == 0) {
      partial += As / Zs - __logf(Zs);
      atomicAdd(counts + mi, 1.0f);
    }
  }
  __syncthreads();

  // ---- GEMM2 (MFMA): q[r][d] = sum_m P[r][m] * E[m][d]
  // wave w owns K-range [256w, 256w+256) (8 k-steps); 4 n-tiles cover d=0..63
  {
    f32x4 q[4];
#pragma unroll
    for (int nt = 0; nt < 4; ++nt) q[nt] = (f32x4){0.f, 0.f, 0.f, 0.f};
    int k0w = wave * 256;
#pragma unroll 2
    for (int ks = 0; ks < 8; ++ks) {
      int k0 = k0w + ks * 32;
      bf16x8 ph, pl;
      cvt8(&s_sc[mn][k0 + mq * 8], ph, pl);  // A row = token mn, k-chunk
#pragma unroll
      for (int nt = 0; nt < 4; ++nt) {
        const short* bp = ETH + (nt * 16 + mn) * 1024 + k0 + mq * 8;
        const short* lp = ETL + (nt * 16 + mn) * 1024 + k0 + mq * 8;
        bf16x8 bh = *(const bf16x8*)bp;
        bf16x8 bl = *(const bf16x8*)lp;
        q[nt] = __builtin_amdgcn_mfma_f32_16x16x32_bf16(ph, bh, q[nt], 0, 0, 0);
        q[nt] = __builtin_amdgcn_mfma_f32_16x16x32_bf16(pl, bh, q[nt], 0, 0, 0);
        q[nt] = __builtin_amdgcn_mfma_f32_16x16x32_bf16(ph, bl, q[nt], 0, 0, 0);
      }
    }
    __syncthreads();  // all reads of s_sc (encodings) complete
    // partial q -> LDS (overlay on s_sc region): qp[w][r][68]
    float* qp = &s_sc[0][0];
#pragma unroll
    for (int nt = 0; nt < 4; ++nt)
#pragma unroll
      for (int reg = 0; reg < 4; ++reg)
        qp[(wave * 16 + mq * 4 + reg) * 68 + nt * 16 + mn] = q[nt][reg];
  }
  __syncthreads();

  // ---- combine partials, write quantized (transposed), recon ----
  {
    int r = tid & 15, dq = tid >> 4;  // consecutive lanes -> consecutive t
    const float* qp = &s_sc[0][0];
    float4 qs = {0.f, 0.f, 0.f, 0.f};
#pragma unroll
    for (int w = 0; w < 4; ++w) {
      float4 v = *(const float4*)&qp[(w * 16 + r) * 68 + 4 * dq];
      qs.x += v.x; qs.y += v.y; qs.z += v.z; qs.w += v.w;
    }
    int t = t0 + r;
    float* ob = outq + ((size_t)b << 18) + (size_t)t;
    int d = 4 * dq;
    ob[(size_t)(d + 0) << 12] = qs.x;
    ob[(size_t)(d + 1) << 12] = qs.y;
    ob[(size_t)(d + 2) << 12] = qs.z;
    ob[(size_t)(d + 3) << 12] = qs.w;
    float4 xv = *(const float4*)&s_x[r][d];
    float dx0 = xv.x - qs.x, dx1 = xv.y - qs.y, dx2 = xv.z - qs.z, dx3 = xv.w - qs.w;
    partial += 0.5f * precision * (dx0 * dx0 + dx1 * dx1 + dx2 * dx2 + dx3 * dx3);
  }
#pragma unroll
  for (int off = 32; off; off >>= 1) partial += __shfl_xor(partial, off);
  if (lane == 0) s_red[wave] = partial;
  __syncthreads();
  if (tid == 0)
    atomicAdd(accum, s_red[0] + s_red[1] + s_red[2] + s_red[3]);
}

__global__ void vq_finalize(const float* __restrict__ ws, float* __restrict__ out) {
  __shared__ float red[4];
  int tid = threadIdx.x;
  float h = 0.f;
  for (int m = tid; m < M_DIM; m += 256) {
    float avg = ws[M_DIM + m] * (1.0f / 32768.0f);
    h += avg * __logf(avg + 1e-10f);
  }
#pragma unroll
  for (int off = 32; off; off >>= 1) h += __shfl_xor(h, off);
  int lane = tid & 63, wave = tid >> 6;
  if (lane == 0) red[wave] = h;
  __syncthreads();
  if (tid == 0) {
    out[0] = ws[2 * M_DIM] * 0.125f;                        // loss = total / B
    out[1] = __expf(-(red[0] + red[1] + red[2] + red[3]));  // perplexity
  }
}

extern "C" void kernel_launch(void* const* d_in, const int* in_sizes, int n_in,
                              void* d_out, int out_size, void* d_ws, size_t ws_size,
                              hipStream_t stream) {
  const float* x = (const float*)d_in[0];
  const float* emb = (const float*)d_in[1];
  const float* lvq = (const float*)d_in[2];
  const float* gum = (const float*)d_in[3];
  const float* temp = (const float*)d_in[4];
  float* out = (float*)d_out;
  float* ws = (float*)d_ws;

  hipLaunchKernelGGL(vq_prep, dim3(4), dim3(256), 0, stream, emb, ws);
  hipLaunchKernelGGL(vq_conv, dim3(256), dim3(256), 0, stream, emb, ws);
  hipLaunchKernelGGL(vq_main, dim3(N_ROWS / TR), dim3(256), 0, stream,
                     x, emb, lvq, gum, temp, out, ws);
  hipLaunchKernelGGL(vq_finalize, dim3(1), dim3(256), 0, stream, ws,
                     out + (size_t)2097152);
}

// Round 4
// 318.943 us; speedup vs baseline: 1.6714x; 1.1530x over previous
//
#include <hip/hip_runtime.h>

// Problem constants (B=8, T=4096, D=64, M=1024, N=32768)
#define T_DIM 4096
#define D_DIM 64
#define M_DIM 1024
#define N_ROWS 32768
#define TR 16   // rows (tokens) per workgroup
#define SC_STRIDE (M_DIM + 4)

typedef __attribute__((ext_vector_type(8))) short bf16x8;
typedef __attribute__((ext_vector_type(4))) float f32x4;

// ws layout: floats [0,1024)=||e||^2, [1024,2048)=counts, [2048]=loss accum.
// shorts from float index 4096 (byte 16384): EH[65536], EL[65536], ETH[65536], ETL[65536]
#define WS_BF16_OFF 4096

__device__ __forceinline__ short f2bfs(float f) {
  union { float f; unsigned u; } v; v.f = f;
  unsigned r = v.u + 0x7fffu + ((v.u >> 16) & 1u);  // RNE
  return (short)(r >> 16);
}
__device__ __forceinline__ float bf2f(short h) {
  union { unsigned u; float f; } v; v.u = ((unsigned)(unsigned short)h) << 16;
  return v.f;
}
// 8 consecutive fp32 -> hi/lo bf16x8
__device__ __forceinline__ void cvt8(const float* p, bf16x8& h8, bf16x8& l8) {
  float4 a = *(const float4*)p, b = *(const float4*)(p + 4);
  float v[8] = {a.x, a.y, a.z, a.w, b.x, b.y, b.z, b.w};
#pragma unroll
  for (int i = 0; i < 8; ++i) {
    short h = f2bfs(v[i]);
    h8[i] = h;
    l8[i] = f2bfs(v[i] - bf2f(h));
  }
}

// split embedding into hi/lo bf16 (row-major + transposed, all coalesced via
// LDS tile), and fold in ||e||^2 + counts/accum zeroing (was vq_prep)
__global__ void vq_conv(const float* __restrict__ emb, float* __restrict__ ws) {
  __shared__ short s_h[64][72], s_l[64][72];
  const int tid = threadIdx.x;
  const int mb = blockIdx.x * 64;  // 16 blocks x 64 codebook rows
  short* EH = (short*)(ws + WS_BF16_OFF);
  short* EL = EH + 65536;
  short* ETH = EL + 65536;
  short* ETL = ETH + 65536;
#pragma unroll
  for (int i = 0; i < 16; ++i) {
    int lin = tid + 256 * i;  // 0..4095 over (ml, d)
    int ml = lin >> 6, d = lin & 63;
    float v = emb[(size_t)(mb + ml) * 64 + d];
    short h = f2bfs(v);
    short l = f2bfs(v - bf2f(h));
    EH[(size_t)(mb + ml) * 64 + d] = h;
    EL[(size_t)(mb + ml) * 64 + d] = l;
    s_h[d][ml] = h;
    s_l[d][ml] = l;
  }
  // ||e||^2 + zero counts (+ zero loss accum once)
  if (tid < 64) {
    const float* e = emb + (size_t)(mb + tid) * 64;
    float s = 0.f;
#pragma unroll
    for (int d = 0; d < 64; d += 4) {
      float4 v = *(const float4*)(e + d);
      s += v.x * v.x + v.y * v.y + v.z * v.z + v.w * v.w;
    }
    ws[mb + tid] = s;
    ws[M_DIM + mb + tid] = 0.f;
  }
  if (blockIdx.x == 0 && tid == 0) ws[2 * M_DIM] = 0.f;
  __syncthreads();
#pragma unroll
  for (int i = 0; i < 16; ++i) {
    int lin = tid + 256 * i;  // now (d, ml)
    int d = lin >> 6, ml = lin & 63;
    ETH[(size_t)d * 1024 + mb + ml] = s_h[d][ml];
    ETL[(size_t)d * 1024 + mb + ml] = s_l[d][ml];
  }
}

__global__ __launch_bounds__(256, 2) void vq_main(
    const float* __restrict__ x, const float* __restrict__ emb,
    const float* __restrict__ lvq, const float* __restrict__ gum,
    const float* __restrict__ temp, float* __restrict__ outq,
    float* __restrict__ ws) {
  __shared__ float s_sc[TR][SC_STRIDE];  // logits -> encodings -> q-partials
  __shared__ float s_x[TR][68];          // x tile (padded)
  __shared__ float s_xx[TR];
  __shared__ float s_red[4];

  const int tid = threadIdx.x;
  const int lane = tid & 63;
  const int wave = tid >> 6;   // 4 waves
  const int mq = lane >> 4;    // quad 0..3
  const int mn = lane & 15;
  const int n0 = blockIdx.x * TR;
  const int b = n0 >> 12;
  const int t0 = n0 & (T_DIM - 1);
  const float precision = __expf(-lvq[0]);
  const float inv_temp = 1.0f / temp[0];
  const float* eew = ws;
  float* counts = ws + M_DIM;
  float* accum = ws + 2 * M_DIM;
  const short* EH = (const short*)(ws + WS_BF16_OFF);
  const short* EL = EH + 65536;
  const short* ETH = EL + 65536;
  const short* ETL = ETH + 65536;

  // ---- stage x tile: x[b][d][t0+tt] ----
  {
    int tt = tid & 15, d0 = tid >> 4;
#pragma unroll
    for (int k = 0; k < 4; ++k) {
      int d = d0 + 16 * k;
      s_x[tt][d] = x[((size_t)b << 18) + ((size_t)d << 12) + (size_t)(t0 + tt)];
    }
  }
  __syncthreads();
  if (tid < TR) {
    float s = 0.f;
#pragma unroll
    for (int d = 0; d < D_DIM; ++d) { float v = s_x[tid][d]; s += v * v; }
    s_xx[tid] = s;
  }
  __syncthreads();

  // ---- GEMM1 (MFMA): logits[r][m] = precision*(x.e - 0.5||x||^2 - 0.5||e||^2)
  // wave w owns m in [256w, 256w+256) = 16 tiles of 16x16; K=64 = 2 k-steps
  // FULLY UNROLLED: acc[] must be compile-time indexed (partial unroll -> scratch!)
  {
    bf16x8 ah0, al0, ah1, al1;
    cvt8(&s_x[mn][mq * 8], ah0, al0);        // k-step 0
    cvt8(&s_x[mn][32 + mq * 8], ah1, al1);   // k-step 1
    float xx4[4];
#pragma unroll
    for (int reg = 0; reg < 4; ++reg) xx4[reg] = s_xx[mq * 4 + reg];
    f32x4 acc[16];
#pragma unroll
    for (int tt = 0; tt < 16; ++tt) acc[tt] = (f32x4){0.f, 0.f, 0.f, 0.f};
#pragma unroll
    for (int tt = 0; tt < 16; ++tt) {
      int m0 = wave * 256 + tt * 16;
      const short* bp = EH + (m0 + mn) * 64 + mq * 8;
      const short* lp = EL + (m0 + mn) * 64 + mq * 8;
      bf16x8 bh0 = *(const bf16x8*)bp;
      bf16x8 bh1 = *(const bf16x8*)(bp + 32);
      bf16x8 bl0 = *(const bf16x8*)lp;
      bf16x8 bl1 = *(const bf16x8*)(lp + 32);
      acc[tt] = __builtin_amdgcn_mfma_f32_16x16x32_bf16(ah0, bh0, acc[tt], 0, 0, 0);
      acc[tt] = __builtin_amdgcn_mfma_f32_16x16x32_bf16(ah1, bh1, acc[tt], 0, 0, 0);
      acc[tt] = __builtin_amdgcn_mfma_f32_16x16x32_bf16(al0, bh0, acc[tt], 0, 0, 0);
      acc[tt] = __builtin_amdgcn_mfma_f32_16x16x32_bf16(al1, bh1, acc[tt], 0, 0, 0);
      acc[tt] = __builtin_amdgcn_mfma_f32_16x16x32_bf16(ah0, bl0, acc[tt], 0, 0, 0);
      acc[tt] = __builtin_amdgcn_mfma_f32_16x16x32_bf16(ah1, bl1, acc[tt], 0, 0, 0);
    }
    // epilogue: C layout col=lane&15, row=(lane>>4)*4+reg
#pragma unroll
    for (int tt = 0; tt < 16; ++tt) {
      int m0 = wave * 256 + tt * 16;
      float eev = eew[m0 + mn];
#pragma unroll
      for (int reg = 0; reg < 4; ++reg) {
        int r = mq * 4 + reg;
        s_sc[r][m0 + mn] = precision * (acc[tt][reg] - 0.5f * (xx4[reg] + eev));
      }
    }
  }
  __syncthreads();

  float partial = 0.f;

  // ---- phase 2: per-row softmaxes (wave w handles rows 4w..4w+3) ----
  for (int rr = 0; rr < 4; ++rr) {
    int r = wave * 4 + rr;
    int n = n0 + r;
    float s[16], g[16];
#pragma unroll
    for (int k = 0; k < 4; ++k) {
      float4 v = *(const float4*)&s_sc[r][4 * lane + 256 * k];
      s[4 * k + 0] = v.x; s[4 * k + 1] = v.y; s[4 * k + 2] = v.z; s[4 * k + 3] = v.w;
    }
    float mx = -1e30f; int mi = 0;
#pragma unroll
    for (int i = 0; i < 16; ++i) {
      int m = 4 * lane + 256 * (i >> 2) + (i & 3);
      if (s[i] > mx) { mx = s[i]; mi = m; }
    }
#pragma unroll
    for (int off = 32; off; off >>= 1) {
      float omx = __shfl_xor(mx, off);
      int omi = __shfl_xor(mi, off);
      if (omx > mx || (omx == mx && omi < mi)) { mx = omx; mi = omi; }
    }
    const float* gn = gum + ((size_t)n << 10);
#pragma unroll
    for (int k = 0; k < 4; ++k) {
      float4 v = *(const float4*)(gn + 4 * lane + 256 * k);
      g[4 * k + 0] = v.x; g[4 * k + 1] = v.y; g[4 * k + 2] = v.z; g[4 * k + 3] = v.w;
    }
    float gmx = -1e30f;
#pragma unroll
    for (int i = 0; i < 16; ++i) {
      float gv = (s[i] + g[i]) * inv_temp;
      g[i] = gv;
      gmx = fmaxf(gmx, gv);
    }
#pragma unroll
    for (int off = 32; off; off >>= 1) gmx = fmaxf(gmx, __shfl_xor(gmx, off));
    float Zs = 0.f, As = 0.f, Zg = 0.f;
#pragma unroll
    for (int i = 0; i < 16; ++i) {
      float a = s[i] - mx;
      float e = __expf(a);
      Zs += e; As += a * e;
      float eg = __expf(g[i] - gmx);
      g[i] = eg;
      Zg += eg;
    }
#pragma unroll
    for (int off = 32; off; off >>= 1) {
      Zs += __shfl_xor(Zs, off);
      As += __shfl_xor(As, off);
      Zg += __shfl_xor(Zg, off);
    }
    float invZg = 1.0f / Zg;
#pragma unroll
    for (int k = 0; k < 4; ++k) {
      float4 w;
      w.x = g[4 * k + 0] * invZg; w.y = g[4 * k + 1] * invZg;
      w.z = g[4 * k + 2] * invZg; w.w = g[4 * k + 3] * invZg;
      *(float4*)&s_sc[r][4 * lane + 256 * k] = w;  // encodings overwrite logits
    }
    if (lane == 0) {
      partial += As / Zs - __logf(Zs);
      atomicAdd(counts + mi, 1.0f);
    }
  }
  __syncthreads();

  // ---- GEMM2 (MFMA): q[r][d] = sum_m P[r][m] * E[m][d]
  // wave w owns K-range [256w, 256w+256) (8 k-steps); 4 n-tiles cover d=0..63
  {
    f32x4 q[4];
#pragma unroll
    for (int nt = 0; nt < 4; ++nt) q[nt] = (f32x4){0.f, 0.f, 0.f, 0.f};
    int k0w = wave * 256;
#pragma unroll 2
    for (int ks = 0; ks < 8; ++ks) {
      int k0 = k0w + ks * 32;
      bf16x8 ph, pl;
      cvt8(&s_sc[mn][k0 + mq * 8], ph, pl);  // A row = token mn, k-chunk
#pragma unroll
      for (int nt = 0; nt < 4; ++nt) {
        const short* bp = ETH + (nt * 16 + mn) * 1024 + k0 + mq * 8;
        const short* lp = ETL + (nt * 16 + mn) * 1024 + k0 + mq * 8;
        bf16x8 bh = *(const bf16x8*)bp;
        bf16x8 bl = *(const bf16x8*)lp;
        q[nt] = __builtin_amdgcn_mfma_f32_16x16x32_bf16(ph, bh, q[nt], 0, 0, 0);
        q[nt] = __builtin_amdgcn_mfma_f32_16x16x32_bf16(pl, bh, q[nt], 0, 0, 0);
        q[nt] = __builtin_amdgcn_mfma_f32_16x16x32_bf16(ph, bl, q[nt], 0, 0, 0);
      }
    }
    __syncthreads();  // all reads of s_sc (encodings) complete
    // partial q -> LDS (overlay on s_sc region): qp[w][r][68]
    float* qp = &s_sc[0][0];
#pragma unroll
    for (int nt = 0; nt < 4; ++nt)
#pragma unroll
      for (int reg = 0; reg < 4; ++reg)
        qp[(wave * 16 + mq * 4 + reg) * 68 + nt * 16 + mn] = q[nt][reg];
  }
  __syncthreads();

  // ---- combine partials, write quantized (transposed), recon ----
  {
    int r = tid & 15, dq = tid >> 4;  // consecutive lanes -> consecutive t
    const float* qp = &s_sc[0][0];
    float4 qs = {0.f, 0.f, 0.f, 0.f};
#pragma unroll
    for (int w = 0; w < 4; ++w) {
      float4 v = *(const float4*)&qp[(w * 16 + r) * 68 + 4 * dq];
      qs.x += v.x; qs.y += v.y; qs.z += v.z; qs.w += v.w;
    }
    int t = t0 + r;
    float* ob = outq + ((size_t)b << 18) + (size_t)t;
    int d = 4 * dq;
    ob[(size_t)(d + 0) << 12] = qs.x;
    ob[(size_t)(d + 1) << 12] = qs.y;
    ob[(size_t)(d + 2) << 12] = qs.z;
    ob[(size_t)(d + 3) << 12] = qs.w;
    float4 xv = *(const float4*)&s_x[r][d];
    float dx0 = xv.x - qs.x, dx1 = xv.y - qs.y, dx2 = xv.z - qs.z, dx3 = xv.w - qs.w;
    partial += 0.5f * precision * (dx0 * dx0 + dx1 * dx1 + dx2 * dx2 + dx3 * dx3);
  }
#pragma unroll
  for (int off = 32; off; off >>= 1) partial += __shfl_xor(partial, off);
  if (lane == 0) s_red[wave] = partial;
  __syncthreads();
  if (tid == 0)
    atomicAdd(accum, s_red[0] + s_red[1] + s_red[2] + s_red[3]);
}

__global__ void vq_finalize(const float* __restrict__ ws, float* __restrict__ out) {
  __shared__ float red[4];
  int tid = threadIdx.x;
  float h = 0.f;
  for (int m = tid; m < M_DIM; m += 256) {
    float avg = ws[M_DIM + m] * (1.0f / 32768.0f);
    h += avg * __logf(avg + 1e-10f);
  }
#pragma unroll
  for (int off = 32; off; off >>= 1) h += __shfl_xor(h, off);
  int lane = tid & 63, wave = tid >> 6;
  if (lane == 0) red[wave] = h;
  __syncthreads();
  if (tid == 0) {
    out[0] = ws[2 * M_DIM] * 0.125f;                        // loss = total / B
    out[1] = __expf(-(red[0] + red[1] + red[2] + red[3]));  // perplexity
  }
}

extern "C" void kernel_launch(void* const* d_in, const int* in_sizes, int n_in,
                              void* d_out, int out_size, void* d_ws, size_t ws_size,
                              hipStream_t stream) {
  const float* x = (const float*)d_in[0];
  const float* emb = (const float*)d_in[1];
  const float* lvq = (const float*)d_in[2];
  const float* gum = (const float*)d_in[3];
  const float* temp = (const float*)d_in[4];
  float* out = (float*)d_out;
  float* ws = (float*)d_ws;

  hipLaunchKernelGGL(vq_conv, dim3(16), dim3(256), 0, stream, emb, ws);
  hipLaunchKernelGGL(vq_main, dim3(N_ROWS / TR), dim3(256), 0, stream,
                     x, emb, lvq, gum, temp, out, ws);
  hipLaunchKernelGGL(vq_finalize, dim3(1), dim3(256), 0, stream, ws,
                     out + (size_t)2097152);
}